// Round 1
// baseline (723.387 us; speedup 1.0000x reference)
//
#include <hip/hip_runtime.h>
#include <math.h>

// ---------------------------------------------------------------------------
// Problem: EdgePreprocess — strain-transform pos & cell, then per-edge
//   edge_vec = pos'[dst] - pos'[src] + cell_shift @ cell'[batch[src]]
//   edge_len = ||edge_vec||
// N_ATOMS=500k, N_EDGES=16M, N_BATCH=128.
// Memory-bound: ~576 MB streaming HBM traffic -> ~92 us floor @ 6.3 TB/s.
// ---------------------------------------------------------------------------

// Kernel A: cell' = cell + cell @ sym(strain), stored row-padded [B][3][4]
// so edge kernel can read rows as float4. Tiny (B=128).
__global__ void cell_kernel(const float* __restrict__ cell,
                            const float* __restrict__ strain,
                            float* __restrict__ cell4, int B) {
    int b = blockIdx.x * blockDim.x + threadIdx.x;
    if (b >= B) return;
    float c[9], s[9], S[9];
#pragma unroll
    for (int i = 0; i < 9; ++i) { c[i] = cell[b * 9 + i]; s[i] = strain[b * 9 + i]; }
#pragma unroll
    for (int i = 0; i < 3; ++i)
#pragma unroll
        for (int j = 0; j < 3; ++j)
            S[i * 3 + j] = 0.5f * (s[i * 3 + j] + s[j * 3 + i]);
#pragma unroll
    for (int i = 0; i < 3; ++i) {
#pragma unroll
        for (int j = 0; j < 3; ++j) {
            float v = c[i * 3 + j];
#pragma unroll
            for (int k = 0; k < 3; ++k) v += c[i * 3 + k] * S[k * 3 + j];
            cell4[b * 12 + i * 4 + j] = v;
        }
        cell4[b * 12 + i * 4 + 3] = 0.0f;
    }
}

// Kernel B: pos' = pos + pos @ sym(strain)[batch], packed as float4
// {x,y,z, int_as_float(batch)} so the edge kernel's atom gather is one
// dwordx4 AND carries the batch id (no separate batch gather).
__global__ void pos_kernel(const float* __restrict__ pos,
                           const int* __restrict__ batch,
                           const float* __restrict__ strain,
                           float4* __restrict__ pos4, int N) {
    int n = blockIdx.x * blockDim.x + threadIdx.x;
    if (n >= N) return;
    float p0 = pos[n * 3 + 0], p1 = pos[n * 3 + 1], p2 = pos[n * 3 + 2];
    int b = batch[n];
    const float* s = strain + (long)b * 9;
    float S[9];
#pragma unroll
    for (int i = 0; i < 3; ++i)
#pragma unroll
        for (int j = 0; j < 3; ++j)
            S[i * 3 + j] = 0.5f * (s[i * 3 + j] + s[j * 3 + i]);
    float q0 = p0 + p0 * S[0] + p1 * S[3] + p2 * S[6];
    float q1 = p1 + p0 * S[1] + p1 * S[4] + p2 * S[7];
    float q2 = p2 + p0 * S[2] + p1 * S[5] + p2 * S[8];
    pos4[n] = make_float4(q0, q1, q2, __int_as_float(b));
}

// Kernel C: main edge kernel, 4 edges per thread so every streaming access
// is an aligned 16B dwordx4 (indices, cell_shift, edge_vec, edge_length).
__global__ void __launch_bounds__(256)
edge_kernel(const int* __restrict__ ei,       // [2,E] int32
            const float* __restrict__ cs,     // [E,3]
            const float4* __restrict__ pos4,  // [N] packed
            const float* __restrict__ cell4,  // [B*12] row-padded
            float* __restrict__ out,          // edge_vec [E*3] ++ edge_len [E]
            long E) {
    float* out_vec = out;
    float* out_len = out + 3 * E;
    long t = (long)blockIdx.x * blockDim.x + threadIdx.x;
    long e0 = t * 4;
    if (e0 >= E) return;

    bool full = (e0 + 3 < E) && ((E & 3) == 0);
    if (full) {
        int4 src4 = *(const int4*)(ei + e0);
        int4 dst4 = *(const int4*)(ei + E + e0);
        float4 c0 = *(const float4*)(cs + e0 * 3 + 0);
        float4 c1 = *(const float4*)(cs + e0 * 3 + 4);
        float4 c2 = *(const float4*)(cs + e0 * 3 + 8);
        float shx[4] = {c0.x, c0.w, c1.z, c2.y};
        float shy[4] = {c0.y, c1.x, c1.w, c2.z};
        float shz[4] = {c0.z, c1.y, c2.x, c2.w};
        int srcs[4] = {src4.x, src4.y, src4.z, src4.w};
        int dsts[4] = {dst4.x, dst4.y, dst4.z, dst4.w};
        float ovec[12], olen[4];
#pragma unroll
        for (int k = 0; k < 4; ++k) {
            float4 ps = pos4[srcs[k]];
            float4 pd = pos4[dsts[k]];
            int b = __float_as_int(ps.w);
            const float* C = cell4 + b * 12;
            float4 r0 = *(const float4*)(C + 0);
            float4 r1 = *(const float4*)(C + 4);
            float4 r2 = *(const float4*)(C + 8);
            float sx = shx[k], sy = shy[k], sz = shz[k];
            float vx = pd.x - ps.x + sx * r0.x + sy * r1.x + sz * r2.x;
            float vy = pd.y - ps.y + sx * r0.y + sy * r1.y + sz * r2.y;
            float vz = pd.z - ps.z + sx * r0.z + sy * r1.z + sz * r2.z;
            ovec[k * 3 + 0] = vx;
            ovec[k * 3 + 1] = vy;
            ovec[k * 3 + 2] = vz;
            olen[k] = sqrtf(vx * vx + vy * vy + vz * vz);
        }
        *(float4*)(out_vec + e0 * 3 + 0) = make_float4(ovec[0], ovec[1], ovec[2], ovec[3]);
        *(float4*)(out_vec + e0 * 3 + 4) = make_float4(ovec[4], ovec[5], ovec[6], ovec[7]);
        *(float4*)(out_vec + e0 * 3 + 8) = make_float4(ovec[8], ovec[9], ovec[10], ovec[11]);
        *(float4*)(out_len + e0) = make_float4(olen[0], olen[1], olen[2], olen[3]);
    } else {
        long e1 = (e0 + 4 < E) ? (e0 + 4) : E;
        for (long e = e0; e < e1; ++e) {
            int s = ei[e], d = ei[E + e];
            float4 ps = pos4[s];
            float4 pd = pos4[d];
            int b = __float_as_int(ps.w);
            const float* C = cell4 + b * 12;
            float sx = cs[e * 3], sy = cs[e * 3 + 1], sz = cs[e * 3 + 2];
            float vx = pd.x - ps.x + sx * C[0] + sy * C[4] + sz * C[8];
            float vy = pd.y - ps.y + sx * C[1] + sy * C[5] + sz * C[9];
            float vz = pd.z - ps.z + sx * C[2] + sy * C[6] + sz * C[10];
            out_vec[e * 3 + 0] = vx;
            out_vec[e * 3 + 1] = vy;
            out_vec[e * 3 + 2] = vz;
            out_len[e] = sqrtf(vx * vx + vy * vy + vz * vz);
        }
    }
}

// Fallback if workspace too small: fully fused, recompute transforms per edge.
__global__ void __launch_bounds__(256)
edge_fused_kernel(const float* __restrict__ pos, const float* __restrict__ cell,
                  const float* __restrict__ cs, const int* __restrict__ ei,
                  const int* __restrict__ batch, const float* __restrict__ strain,
                  float* __restrict__ out, long E) {
    float* out_vec = out;
    float* out_len = out + 3 * E;
    long e = (long)blockIdx.x * blockDim.x + threadIdx.x;
    if (e >= E) return;
    int s = ei[e], d = ei[E + e];
    int bs = batch[s], bd = batch[d];
    float Ss[9], Sd[9];
#pragma unroll
    for (int i = 0; i < 3; ++i)
#pragma unroll
        for (int j = 0; j < 3; ++j) {
            Ss[i * 3 + j] = 0.5f * (strain[bs * 9 + i * 3 + j] + strain[bs * 9 + j * 3 + i]);
            Sd[i * 3 + j] = 0.5f * (strain[bd * 9 + i * 3 + j] + strain[bd * 9 + j * 3 + i]);
        }
    float ps0 = pos[s * 3], ps1 = pos[s * 3 + 1], ps2 = pos[s * 3 + 2];
    float pd0 = pos[d * 3], pd1 = pos[d * 3 + 1], pd2 = pos[d * 3 + 2];
    float qs[3], qd[3];
#pragma unroll
    for (int j = 0; j < 3; ++j) {
        qs[j] = (j == 0 ? ps0 : j == 1 ? ps1 : ps2) + ps0 * Ss[j] + ps1 * Ss[3 + j] + ps2 * Ss[6 + j];
        qd[j] = (j == 0 ? pd0 : j == 1 ? pd1 : pd2) + pd0 * Sd[j] + pd1 * Sd[3 + j] + pd2 * Sd[6 + j];
    }
    // cell'(bs) rows
    float Cn[9];
#pragma unroll
    for (int i = 0; i < 3; ++i)
#pragma unroll
        for (int j = 0; j < 3; ++j) {
            float v = cell[bs * 9 + i * 3 + j];
#pragma unroll
            for (int k = 0; k < 3; ++k) v += cell[bs * 9 + i * 3 + k] * Ss[k * 3 + j];
            Cn[i * 3 + j] = v;
        }
    float sx = cs[e * 3], sy = cs[e * 3 + 1], sz = cs[e * 3 + 2];
    float vx = qd[0] - qs[0] + sx * Cn[0] + sy * Cn[3] + sz * Cn[6];
    float vy = qd[1] - qs[1] + sx * Cn[1] + sy * Cn[4] + sz * Cn[7];
    float vz = qd[2] - qs[2] + sx * Cn[2] + sy * Cn[5] + sz * Cn[8];
    out_vec[e * 3 + 0] = vx;
    out_vec[e * 3 + 1] = vy;
    out_vec[e * 3 + 2] = vz;
    out_len[e] = sqrtf(vx * vx + vy * vy + vz * vz);
}

extern "C" void kernel_launch(void* const* d_in, const int* in_sizes, int n_in,
                              void* d_out, int out_size, void* d_ws, size_t ws_size,
                              hipStream_t stream) {
    const float* pos    = (const float*)d_in[0];  // [N,3]
    const float* cell   = (const float*)d_in[1];  // [B,3,3]
    const float* cs     = (const float*)d_in[2];  // [E,3]
    const int*   ei     = (const int*)d_in[3];    // [2,E]
    const int*   batch  = (const int*)d_in[4];    // [N]
    const float* strain = (const float*)d_in[5];  // [B,3,3]
    int  N = in_sizes[0] / 3;
    int  B = in_sizes[1] / 9;
    long E = (long)in_sizes[2] / 3;
    float* out = (float*)d_out;

    size_t pos4_bytes  = (size_t)N * sizeof(float4);
    size_t cell4_bytes = (size_t)B * 12 * sizeof(float);

    if (ws_size >= pos4_bytes + cell4_bytes) {
        float4* pos4  = (float4*)d_ws;
        float*  cell4 = (float*)((char*)d_ws + pos4_bytes);
        hipLaunchKernelGGL(cell_kernel, dim3((B + 63) / 64), dim3(64), 0, stream,
                           cell, strain, cell4, B);
        hipLaunchKernelGGL(pos_kernel, dim3((N + 255) / 256), dim3(256), 0, stream,
                           pos, batch, strain, pos4, N);
        long tasks = (E + 3) / 4;
        hipLaunchKernelGGL(edge_kernel, dim3((unsigned)((tasks + 255) / 256)), dim3(256), 0,
                           stream, ei, cs, pos4, cell4, out, E);
    } else {
        hipLaunchKernelGGL(edge_fused_kernel, dim3((unsigned)((E + 255) / 256)), dim3(256), 0,
                           stream, pos, cell, cs, ei, batch, strain, out, E);
    }
}

// Round 3
// 652.661 us; speedup vs baseline: 1.1084x; 1.1084x over previous
//
#include <hip/hip_runtime.h>
#include <hip/hip_fp16.h>
#include <math.h>

// ---------------------------------------------------------------------------
// EdgePreprocess — strain-transform pos & cell, then per-edge
//   edge_vec = pos'[dst] - pos'[src] + cell_shift @ cell'[batch[src]]
//   edge_len = ||edge_vec||
// N_ATOMS=500k, N_EDGES=16M, N_BATCH=128.
//
// R2/R3 design notes:
//  - Atom table packed to 8 B: {fp16 x, fp16 y, fp16 z, u16 batch}. 500k x 8B
//    = 4 MB -> fits per-XCD L2 (R1's 16 B table = 8 MB thrashed it:
//    FETCH_SIZE 1.29 GB vs ~330 MB streaming ideal).
//  - All streaming loads/stores (edge_index, cell_shift, out) are
//    non-temporal so they don't evict the atom table from L2.
//  - cell' table is 6 KB row-padded fp32 -> L1-resident.
//  - R3 fix: __builtin_nontemporal_* requires native clang vector types,
//    not HIP_vector_type structs -> use ext_vector_type aliases.
// ---------------------------------------------------------------------------

typedef int   vint4   __attribute__((ext_vector_type(4)));
typedef float vfloat4 __attribute__((ext_vector_type(4)));

// Kernel A: cell' = cell + cell @ sym(strain), stored row-padded [B][3][4].
__global__ void cell_kernel(const float* __restrict__ cell,
                            const float* __restrict__ strain,
                            float* __restrict__ cell4, int B) {
    int b = blockIdx.x * blockDim.x + threadIdx.x;
    if (b >= B) return;
    float c[9], s[9], S[9];
#pragma unroll
    for (int i = 0; i < 9; ++i) { c[i] = cell[b * 9 + i]; s[i] = strain[b * 9 + i]; }
#pragma unroll
    for (int i = 0; i < 3; ++i)
#pragma unroll
        for (int j = 0; j < 3; ++j)
            S[i * 3 + j] = 0.5f * (s[i * 3 + j] + s[j * 3 + i]);
#pragma unroll
    for (int i = 0; i < 3; ++i) {
#pragma unroll
        for (int j = 0; j < 3; ++j) {
            float v = c[i * 3 + j];
#pragma unroll
            for (int k = 0; k < 3; ++k) v += c[i * 3 + k] * S[k * 3 + j];
            cell4[b * 12 + i * 4 + j] = v;
        }
        cell4[b * 12 + i * 4 + 3] = 0.0f;
    }
}

// Kernel B: pos' = pos + pos @ sym(strain)[batch], packed 8 B/atom:
//   w0 = fp16(x) | fp16(y)<<16 ; w1 = fp16(z) | batch<<16
__global__ void __launch_bounds__(256)
pos_kernel(const float* __restrict__ pos,
           const int* __restrict__ batch,
           const float* __restrict__ strain,
           uint2* __restrict__ posp, int N) {
    int t = blockIdx.x * blockDim.x + threadIdx.x;
    int n0 = t * 4;
    if (n0 >= N) return;

    if (n0 + 3 < N) {
        vfloat4 a  = *(const vfloat4*)(pos + n0 * 3 + 0);
        vfloat4 b4 = *(const vfloat4*)(pos + n0 * 3 + 4);
        vfloat4 c4 = *(const vfloat4*)(pos + n0 * 3 + 8);
        float px[4] = {a.x, a.w, b4.z, c4.y};
        float py[4] = {a.y, b4.x, b4.w, c4.z};
        float pz[4] = {a.z, b4.y, c4.x, c4.w};
        vint4 bb = *(const vint4*)(batch + n0);
        int bs[4] = {bb.x, bb.y, bb.z, bb.w};
#pragma unroll
        for (int k = 0; k < 4; ++k) {
            const float* s = strain + (long)bs[k] * 9;
            float S[9];
#pragma unroll
            for (int i = 0; i < 3; ++i)
#pragma unroll
                for (int j = 0; j < 3; ++j)
                    S[i * 3 + j] = 0.5f * (s[i * 3 + j] + s[j * 3 + i]);
            float q0 = px[k] + px[k] * S[0] + py[k] * S[3] + pz[k] * S[6];
            float q1 = py[k] + px[k] * S[1] + py[k] * S[4] + pz[k] * S[7];
            float q2 = pz[k] + px[k] * S[2] + py[k] * S[5] + pz[k] * S[8];
            uint32_t w0 = (uint32_t)__half_as_ushort(__float2half_rn(q0)) |
                          ((uint32_t)__half_as_ushort(__float2half_rn(q1)) << 16);
            uint32_t w1 = (uint32_t)__half_as_ushort(__float2half_rn(q2)) |
                          ((uint32_t)bs[k] << 16);
            posp[n0 + k] = make_uint2(w0, w1);
        }
    } else {
        for (int n = n0; n < N; ++n) {
            float p0 = pos[n * 3 + 0], p1 = pos[n * 3 + 1], p2 = pos[n * 3 + 2];
            int b = batch[n];
            const float* s = strain + (long)b * 9;
            float S[9];
#pragma unroll
            for (int i = 0; i < 3; ++i)
#pragma unroll
                for (int j = 0; j < 3; ++j)
                    S[i * 3 + j] = 0.5f * (s[i * 3 + j] + s[j * 3 + i]);
            float q0 = p0 + p0 * S[0] + p1 * S[3] + p2 * S[6];
            float q1 = p1 + p0 * S[1] + p1 * S[4] + p2 * S[7];
            float q2 = p2 + p0 * S[2] + p1 * S[5] + p2 * S[8];
            uint32_t w0 = (uint32_t)__half_as_ushort(__float2half_rn(q0)) |
                          ((uint32_t)__half_as_ushort(__float2half_rn(q1)) << 16);
            uint32_t w1 = (uint32_t)__half_as_ushort(__float2half_rn(q2)) |
                          ((uint32_t)b << 16);
            posp[n] = make_uint2(w0, w1);
        }
    }
}

__device__ __forceinline__ void unpack_pos(uint2 p, float& x, float& y, float& z, int& b) {
    x = __half2float(__ushort_as_half((unsigned short)(p.x & 0xffffu)));
    y = __half2float(__ushort_as_half((unsigned short)(p.x >> 16)));
    z = __half2float(__ushort_as_half((unsigned short)(p.y & 0xffffu)));
    b = (int)(p.y >> 16);
}

// Kernel C: main edge kernel, 4 edges/thread. Streaming traffic is
// non-temporal (keeps the 4 MB atom table L2-resident).
__global__ void __launch_bounds__(256)
edge_kernel(const int* __restrict__ ei,       // [2,E] int32
            const float* __restrict__ cs,     // [E,3]
            const uint2* __restrict__ posp,   // [N] packed 8B
            const float* __restrict__ cell4,  // [B*12] row-padded
            float* __restrict__ out,          // edge_vec [E*3] ++ edge_len [E]
            long E) {
    float* out_vec = out;
    float* out_len = out + 3 * E;
    long t = (long)blockIdx.x * blockDim.x + threadIdx.x;
    long e0 = t * 4;
    if (e0 >= E) return;

    bool full = (e0 + 3 < E) && ((E & 3) == 0);
    if (full) {
        vint4 src4 = __builtin_nontemporal_load((const vint4*)(ei + e0));
        vint4 dst4 = __builtin_nontemporal_load((const vint4*)(ei + E + e0));
        vfloat4 c0 = __builtin_nontemporal_load((const vfloat4*)(cs + e0 * 3 + 0));
        vfloat4 c1 = __builtin_nontemporal_load((const vfloat4*)(cs + e0 * 3 + 4));
        vfloat4 c2 = __builtin_nontemporal_load((const vfloat4*)(cs + e0 * 3 + 8));
        float shx[4] = {c0.x, c0.w, c1.z, c2.y};
        float shy[4] = {c0.y, c1.x, c1.w, c2.z};
        float shz[4] = {c0.z, c1.y, c2.x, c2.w};
        int srcs[4] = {src4.x, src4.y, src4.z, src4.w};
        int dsts[4] = {dst4.x, dst4.y, dst4.z, dst4.w};
        // issue all 8 gathers up-front (independent, overlap latency)
        uint2 ps[4], pd[4];
#pragma unroll
        for (int k = 0; k < 4; ++k) ps[k] = posp[srcs[k]];
#pragma unroll
        for (int k = 0; k < 4; ++k) pd[k] = posp[dsts[k]];
        float ovec[12], olen[4];
#pragma unroll
        for (int k = 0; k < 4; ++k) {
            float sxp, syp, szp, dxp, dyp, dzp; int b, bd_;
            unpack_pos(ps[k], sxp, syp, szp, b);
            unpack_pos(pd[k], dxp, dyp, dzp, bd_);
            (void)bd_;
            const float* C = cell4 + b * 12;
            vfloat4 r0 = *(const vfloat4*)(C + 0);
            vfloat4 r1 = *(const vfloat4*)(C + 4);
            vfloat4 r2 = *(const vfloat4*)(C + 8);
            float sx = shx[k], sy = shy[k], sz = shz[k];
            float vx = dxp - sxp + sx * r0.x + sy * r1.x + sz * r2.x;
            float vy = dyp - syp + sx * r0.y + sy * r1.y + sz * r2.y;
            float vz = dzp - szp + sx * r0.z + sy * r1.z + sz * r2.z;
            ovec[k * 3 + 0] = vx;
            ovec[k * 3 + 1] = vy;
            ovec[k * 3 + 2] = vz;
            olen[k] = sqrtf(vx * vx + vy * vy + vz * vz);
        }
        vfloat4 o0 = {ovec[0], ovec[1], ovec[2], ovec[3]};
        vfloat4 o1 = {ovec[4], ovec[5], ovec[6], ovec[7]};
        vfloat4 o2 = {ovec[8], ovec[9], ovec[10], ovec[11]};
        vfloat4 ol = {olen[0], olen[1], olen[2], olen[3]};
        __builtin_nontemporal_store(o0, (vfloat4*)(out_vec + e0 * 3 + 0));
        __builtin_nontemporal_store(o1, (vfloat4*)(out_vec + e0 * 3 + 4));
        __builtin_nontemporal_store(o2, (vfloat4*)(out_vec + e0 * 3 + 8));
        __builtin_nontemporal_store(ol, (vfloat4*)(out_len + e0));
    } else {
        long e1 = (e0 + 4 < E) ? (e0 + 4) : E;
        for (long e = e0; e < e1; ++e) {
            int s = ei[e], d = ei[E + e];
            float sxp, syp, szp, dxp, dyp, dzp; int b, bd_;
            unpack_pos(posp[s], sxp, syp, szp, b);
            unpack_pos(posp[d], dxp, dyp, dzp, bd_);
            (void)bd_;
            const float* C = cell4 + b * 12;
            float sx = cs[e * 3], sy = cs[e * 3 + 1], sz = cs[e * 3 + 2];
            float vx = dxp - sxp + sx * C[0] + sy * C[4] + sz * C[8];
            float vy = dyp - syp + sx * C[1] + sy * C[5] + sz * C[9];
            float vz = dzp - szp + sx * C[2] + sy * C[6] + sz * C[10];
            out_vec[e * 3 + 0] = vx;
            out_vec[e * 3 + 1] = vy;
            out_vec[e * 3 + 2] = vz;
            out_len[e] = sqrtf(vx * vx + vy * vy + vz * vz);
        }
    }
}

// Fallback if workspace too small: fully fused, recompute transforms per edge.
__global__ void __launch_bounds__(256)
edge_fused_kernel(const float* __restrict__ pos, const float* __restrict__ cell,
                  const float* __restrict__ cs, const int* __restrict__ ei,
                  const int* __restrict__ batch, const float* __restrict__ strain,
                  float* __restrict__ out, long E) {
    float* out_vec = out;
    float* out_len = out + 3 * E;
    long e = (long)blockIdx.x * blockDim.x + threadIdx.x;
    if (e >= E) return;
    int s = ei[e], d = ei[E + e];
    int bs = batch[s], bd = batch[d];
    float Ss[9], Sd[9];
#pragma unroll
    for (int i = 0; i < 3; ++i)
#pragma unroll
        for (int j = 0; j < 3; ++j) {
            Ss[i * 3 + j] = 0.5f * (strain[bs * 9 + i * 3 + j] + strain[bs * 9 + j * 3 + i]);
            Sd[i * 3 + j] = 0.5f * (strain[bd * 9 + i * 3 + j] + strain[bd * 9 + j * 3 + i]);
        }
    float ps0 = pos[s * 3], ps1 = pos[s * 3 + 1], ps2 = pos[s * 3 + 2];
    float pd0 = pos[d * 3], pd1 = pos[d * 3 + 1], pd2 = pos[d * 3 + 2];
    float qs[3], qd[3];
#pragma unroll
    for (int j = 0; j < 3; ++j) {
        qs[j] = (j == 0 ? ps0 : j == 1 ? ps1 : ps2) + ps0 * Ss[j] + ps1 * Ss[3 + j] + ps2 * Ss[6 + j];
        qd[j] = (j == 0 ? pd0 : j == 1 ? pd1 : pd2) + pd0 * Sd[j] + pd1 * Sd[3 + j] + pd2 * Sd[6 + j];
    }
    float Cn[9];
#pragma unroll
    for (int i = 0; i < 3; ++i)
#pragma unroll
        for (int j = 0; j < 3; ++j) {
            float v = cell[bs * 9 + i * 3 + j];
#pragma unroll
            for (int k = 0; k < 3; ++k) v += cell[bs * 9 + i * 3 + k] * Ss[k * 3 + j];
            Cn[i * 3 + j] = v;
        }
    float sx = cs[e * 3], sy = cs[e * 3 + 1], sz = cs[e * 3 + 2];
    float vx = qd[0] - qs[0] + sx * Cn[0] + sy * Cn[3] + sz * Cn[6];
    float vy = qd[1] - qs[1] + sx * Cn[1] + sy * Cn[4] + sz * Cn[7];
    float vz = qd[2] - qs[2] + sx * Cn[2] + sy * Cn[5] + sz * Cn[8];
    out_vec[e * 3 + 0] = vx;
    out_vec[e * 3 + 1] = vy;
    out_vec[e * 3 + 2] = vz;
    out_len[e] = sqrtf(vx * vx + vy * vy + vz * vz);
}

extern "C" void kernel_launch(void* const* d_in, const int* in_sizes, int n_in,
                              void* d_out, int out_size, void* d_ws, size_t ws_size,
                              hipStream_t stream) {
    const float* pos    = (const float*)d_in[0];  // [N,3]
    const float* cell   = (const float*)d_in[1];  // [B,3,3]
    const float* cs     = (const float*)d_in[2];  // [E,3]
    const int*   ei     = (const int*)d_in[3];    // [2,E]
    const int*   batch  = (const int*)d_in[4];    // [N]
    const float* strain = (const float*)d_in[5];  // [B,3,3]
    int  N = in_sizes[0] / 3;
    int  B = in_sizes[1] / 9;
    long E = (long)in_sizes[2] / 3;
    float* out = (float*)d_out;

    size_t posp_bytes  = (size_t)N * sizeof(uint2);
    size_t cell4_bytes = (size_t)B * 12 * sizeof(float);

    if (ws_size >= posp_bytes + cell4_bytes) {
        uint2* posp  = (uint2*)d_ws;
        float* cell4 = (float*)((char*)d_ws + posp_bytes);
        hipLaunchKernelGGL(cell_kernel, dim3((B + 63) / 64), dim3(64), 0, stream,
                           cell, strain, cell4, B);
        int ptasks = (N + 3) / 4;
        hipLaunchKernelGGL(pos_kernel, dim3((ptasks + 255) / 256), dim3(256), 0, stream,
                           pos, batch, strain, posp, N);
        long tasks = (E + 3) / 4;
        hipLaunchKernelGGL(edge_kernel, dim3((unsigned)((tasks + 255) / 256)), dim3(256), 0,
                           stream, ei, cs, posp, cell4, out, E);
    } else {
        hipLaunchKernelGGL(edge_fused_kernel, dim3((unsigned)((E + 255) / 256)), dim3(256), 0,
                           stream, pos, cell, cs, ei, batch, strain, out, E);
    }
}